// Round 17
// baseline (1517.493 us; speedup 1.0000x reference)
//
#include <hip/hip_runtime.h>
#include <hip/hip_bf16.h>
#include <stdint.h>

#define N_RES 4096
#define BATCH 8
#define T_STEPS 256
#define VOCAB 32000
#define R_OUT 512
#define NNZ 131072
#define NNZ_CAP 163840
#define TEAMS 8             // one per batch
#define SLICES 16           // WGs per team
#define ROWS_PS 256         // rows per WG
#define NWG (TEAMS*SLICES)  // 128
#define CSR_CAP 10240       // entries per slice in LDS (mean ~9088, +11 sigma)

typedef _Float16 v8h __attribute__((ext_vector_type(8)));
typedef float v4f __attribute__((ext_vector_type(4)));

static __device__ __forceinline__ unsigned short f2h(float f) {
    _Float16 h = (_Float16)f;
    unsigned short u;
    __builtin_memcpy(&u, &h, 2);
    return u;
}
static __device__ __forceinline__ float h2f(unsigned short u) {
    _Float16 h;
    __builtin_memcpy(&h, &u, 2);
    return (float)h;
}

// ---------------- fused init: zero csr, cnt, flags, hx (one node) ----------------
// hx MUST be zeroed every launch: tags gate reads, and a graph replay would
// otherwise leave last-run tags 254/255 that ALIAS this run's epochs 254/255
// (the no-ack flag can outrun the payload -> stale word validates). With
// hx zeroed, same-parity stale tags are always e-2 != e (or 0) -> safe.

#define FLAG_WORDS (TEAMS * SLICES * 32)        // 4096 u32
#define HX_WORDS   (2 * TEAMS * 4096)           // 65536 u32
#define INIT_WORDS (NNZ_CAP + 4096 + FLAG_WORDS + HX_WORDS)

__global__ __launch_bounds__(256) void k_init(unsigned* __restrict__ csr,
                                              int* __restrict__ cnt,
                                              unsigned* __restrict__ flags,
                                              unsigned* __restrict__ hx) {
    int i = blockIdx.x * 256 + threadIdx.x;
    if (i < NNZ_CAP) csr[i] = 0u;
    else if (i < NNZ_CAP + 4096) cnt[i - NNZ_CAP] = 0;
    else if (i < NNZ_CAP + 4096 + FLAG_WORDS) flags[i - NNZ_CAP - 4096] = 0u;
    else if (i < INIT_WORDS) hx[i - NNZ_CAP - 4096 - FLAG_WORDS] = 0u;
}

// ---------------- CSR build ----------------

__global__ __launch_bounds__(256) void k_hist(const int* __restrict__ rows,
                                              int* __restrict__ cnt) {
    int i = blockIdx.x * 256 + threadIdx.x;
    if (i < NNZ) atomicAdd(&cnt[rows[i]], 1);
}

// padded scan: each row's span rounded up to multiple of 8
__global__ __launch_bounds__(1024) void k_scan(const int* __restrict__ cnt,
                                               int* __restrict__ row_ptr,
                                               int* __restrict__ cursor) {
    __shared__ int sm[1024];
    int t = threadIdx.x;
    int base = t * 4;
    int c0 = (cnt[base] + 7) & ~7;
    int c1 = (cnt[base + 1] + 7) & ~7;
    int c2 = (cnt[base + 2] + 7) & ~7;
    int c3 = (cnt[base + 3] + 7) & ~7;
    int s = c0 + c1 + c2 + c3;
    sm[t] = s;
    __syncthreads();
    for (int off = 1; off < 1024; off <<= 1) {
        int v = (t >= off) ? sm[t - off] : 0;
        __syncthreads();
        sm[t] += v;
        __syncthreads();
    }
    int run = sm[t] - s;
    row_ptr[base] = run;     cursor[base] = run;     run += c0;
    row_ptr[base + 1] = run; cursor[base + 1] = run; run += c1;
    row_ptr[base + 2] = run; cursor[base + 2] = run; run += c2;
    row_ptr[base + 3] = run; cursor[base + 3] = run; run += c3;
    if (t == 1023) row_ptr[4096] = run;
}

// packed CSR entry: plane BYTE offset (col*4) in hi16, f16 value in lo16.
__global__ __launch_bounds__(256) void k_fill(const int* __restrict__ rows,
                                              const int* __restrict__ cols,
                                              const float* __restrict__ vals,
                                              int* __restrict__ cursor,
                                              unsigned* __restrict__ csr) {
    int i = blockIdx.x * 256 + threadIdx.x;
    if (i < NNZ) {
        int r = rows[i];
        unsigned off = (unsigned)(cols[i] << 2);
        int p = atomicAdd(&cursor[r], 1);
        csr[p] = (off << 16) | (unsigned)f2h(vals[i]);
    }
}

// ---------------- fused f32 -> f16 convert: B_w then A_w (one node) ----------------

#define NB8 (R_OUT * N_RES / 8)     // 262144 B_w octets
#define NA8 (VOCAB * R_OUT / 8)     // 2048000 A_w octets

__global__ __launch_bounds__(256) void k_cvt2(const float* __restrict__ Bw,
                                              unsigned short* __restrict__ Bwh,
                                              const float* __restrict__ Aw,
                                              unsigned short* __restrict__ Awh) {
    int i = blockIdx.x * 256 + threadIdx.x;
    const float* src;
    unsigned short* dst;
    int j;
    if (i < NB8) { src = Bw; dst = Bwh; j = i * 8; }
    else if (i < NB8 + NA8) { src = Aw; dst = Awh; j = (i - NB8) * 8; }
    else return;
    float4 a0 = *reinterpret_cast<const float4*>(src + j);
    float4 a1 = *reinterpret_cast<const float4*>(src + j + 4);
    unsigned short o[8] = { f2h(a0.x), f2h(a0.y), f2h(a0.z), f2h(a0.w),
                            f2h(a1.x), f2h(a1.y), f2h(a1.z), f2h(a1.w) };
    *reinterpret_cast<uint4*>(dst + j) = *reinterpret_cast<const uint4*>(o);
}

// ---------------- persistent recurrence: r14 protocol, identity plane ----------------
// 128 WGs x 256 threads. team = wg&7, slice = wg>>3 (256 rows).
// Publish: ONE relaxed agent store of (epoch<<16)|f16(h) per thread; sync;
// tid0 flag store (no vmcnt ack -- tag catches flag-outruns-payload).
// Gate: tid<16 poll team flags; sync. Pull: 4x dwordx4 sc0 sc1 (16B/lane,
// coalesced), tag-validate, retry stale quads (64 budget, then per-word
// agent fallback -> no hang). Refill: quad q -> rows q*1024+4*tid..+3, ONE
// float4 LDS write (identity layout -> conflict-free).
// Replay safety: hx AND flags zeroed every launch (see k_init comment).

__global__ __launch_bounds__(256) void k_steps(const int* __restrict__ rowptr,
                                               const unsigned* __restrict__ csr,
                                               const float* __restrict__ W_in,
                                               const int* __restrict__ x,
                                               const float* __restrict__ a,
                                               unsigned short* __restrict__ Hb,
                                               unsigned* __restrict__ hx,
                                               unsigned* __restrict__ flags) {
    __shared__ float plane[4096];                       // 16 KB, identity
    __shared__ __align__(16) unsigned lcsr[CSR_CAP];    // 40 KB
    __shared__ int ltok[T_STEPS];                       // 1 KB

    int wg = blockIdx.x;
    int tid = threadIdx.x;
    int team = wg & 7;
    int slice = wg >> 3;
    int r_own = slice * ROWS_PS + tid;

    ltok[tid] = x[team * T_STEPS + tid];

    int j0 = rowptr[slice * ROWS_PS];
    int j1 = rowptr[slice * ROWS_PS + ROWS_PS];
    int cntE = j1 - j0;
    if (cntE > CSR_CAP) cntE = CSR_CAP;
    {
        const uint4* src = reinterpret_cast<const uint4*>(csr + j0);
        int n4 = cntE >> 2;
        for (int k = tid; k < n4; k += 256)
            reinterpret_cast<uint4*>(lcsr)[k] = src[k];
    }
    for (int k = tid; k < 4096; k += 256) plane[k] = 0.f;

    int js = rowptr[r_own] - j0;
    int je = rowptr[r_own + 1] - j0;
    if (js > CSR_CAP) js = CSR_CAP;
    if (je > CSR_CAP) je = CSR_CAP;
    float av = a[r_own];
    float oma = 1.f - av;
    __syncthreads();

    float u_cur = W_in[(size_t)ltok[0] * N_RES + r_own];

    for (int t = 0; t < T_STEPS; ++t) {
        float u_nxt = 0.f;
        if (t + 1 < T_STEPS)
            u_nxt = W_in[(size_t)ltok[t + 1] * N_RES + r_own];   // long shadow

        float acc = 0.f;
        for (int j = js; j < je; j += 8) {
            uint4 e0 = *reinterpret_cast<const uint4*>(lcsr + j);
            uint4 e1 = *reinterpret_cast<const uint4*>(lcsr + j + 4);
            unsigned ee[8] = { e0.x, e0.y, e0.z, e0.w, e1.x, e1.y, e1.z, e1.w };
#pragma unroll
            for (int q = 0; q < 8; ++q) {
                float g = *reinterpret_cast<const float*>(
                    reinterpret_cast<const char*>(plane) + (ee[q] >> 16));
                acc += h2f((unsigned short)(ee[q] & 0xffffu)) * g;
            }
        }
        float hold = plane[r_own];
        float pre = u_cur + acc;
        pre = fminf(fmaxf(pre, -10.f), 10.f);
        float ex = __expf(2.f * pre);
        float th = 1.f - 2.f / (ex + 1.f);
        float hv = oma * hold + av * th;
        unsigned short hv16 = f2h(hv);

        if (t == T_STEPS - 1) {
            Hb[((size_t)(team * T_STEPS + t) << 12) + r_own] = hv16;
            break;
        }

        unsigned e = (unsigned)(t + 1);
        unsigned* xb = hx + (((size_t)(e & 1u) * TEAMS + team) << 12);

        // publish own row: tagged word, fire-and-forget (coalesced per wave)
        __hip_atomic_store(xb + r_own, (e << 16) | (unsigned)hv16,
                           __ATOMIC_RELAXED, __HIP_MEMORY_SCOPE_AGENT);
        __syncthreads();                     // all waves issued their stores
        if (tid == 0)
            __hip_atomic_store(flags + (team * SLICES + slice) * 32, e,
                               __ATOMIC_RELAXED, __HIP_MEMORY_SCOPE_AGENT);

        // off-critical-path work in the flag-propagation shadow
        Hb[((size_t)(team * T_STEPS + t) << 12) + r_own] = hv16;

        // gate: tid<16 poll the 16 team flags
        if (tid < SLICES) {
            const unsigned* fp = flags + (team * SLICES + tid) * 32;
            while (__hip_atomic_load(fp, __ATOMIC_RELAXED,
                                     __HIP_MEMORY_SCOPE_AGENT) < e) {}
        }
        __syncthreads();                     // also: all gathers from plane done

        // bulk pull: 4x dwordx4 (16B/lane, fully coalesced), tag-validated
        uint4 v0, v1, v2, v3;
        const char* p0 = reinterpret_cast<const char*>(xb) + (size_t)tid * 16;
        const char* p1 = p0 + 4096;
        const char* p2 = p0 + 8192;
        const char* p3 = p0 + 12288;
        asm volatile(
            "global_load_dwordx4 %0, %4, off sc0 sc1\n\t"
            "global_load_dwordx4 %1, %5, off sc0 sc1\n\t"
            "global_load_dwordx4 %2, %6, off sc0 sc1\n\t"
            "global_load_dwordx4 %3, %7, off sc0 sc1\n\t"
            "s_waitcnt vmcnt(0)"
            : "=&v"(v0), "=&v"(v1), "=&v"(v2), "=&v"(v3)
            : "v"(p0), "v"(p1), "v"(p2), "v"(p3)
            : "memory");
#define QOK(v) (((v.x >> 16) == e) && ((v.y >> 16) == e) && \
                ((v.z >> 16) == e) && ((v.w >> 16) == e))
        int tries = 0;
        while (!(QOK(v0) && QOK(v1) && QOK(v2) && QOK(v3)) && tries <= 64) {
            ++tries;
            if (!QOK(v0)) asm volatile("global_load_dwordx4 %0, %1, off sc0 sc1\n\ts_waitcnt vmcnt(0)" : "=&v"(v0) : "v"(p0) : "memory");
            if (!QOK(v1)) asm volatile("global_load_dwordx4 %0, %1, off sc0 sc1\n\ts_waitcnt vmcnt(0)" : "=&v"(v1) : "v"(p1) : "memory");
            if (!QOK(v2)) asm volatile("global_load_dwordx4 %0, %1, off sc0 sc1\n\ts_waitcnt vmcnt(0)" : "=&v"(v2) : "v"(p2) : "memory");
            if (!QOK(v3)) asm volatile("global_load_dwordx4 %0, %1, off sc0 sc1\n\ts_waitcnt vmcnt(0)" : "=&v"(v3) : "v"(p3) : "memory");
        }
        if (tries > 64) {
            // guaranteed fallback: per-word agent atomics (always visible)
            unsigned w[16];
#pragma unroll
            for (int k = 0; k < 16; ++k) {
                const unsigned* wp = xb + (k >> 2) * 1024 + tid * 4 + (k & 3);
                unsigned g = __hip_atomic_load(wp, __ATOMIC_RELAXED, __HIP_MEMORY_SCOPE_AGENT);
                while ((g >> 16) != e)
                    g = __hip_atomic_load(wp, __ATOMIC_RELAXED, __HIP_MEMORY_SCOPE_AGENT);
                w[k] = g;
            }
            v0 = (uint4){w[0], w[1], w[2], w[3]};
            v1 = (uint4){w[4], w[5], w[6], w[7]};
            v2 = (uint4){w[8], w[9], w[10], w[11]};
            v3 = (uint4){w[12], w[13], w[14], w[15]};
        }
#undef QOK
        // refill: quad q covers rows q*1024 + 4*tid .. +3 -> ONE float4 write
        {
            uint4 qs[4] = { v0, v1, v2, v3 };
#pragma unroll
            for (int q = 0; q < 4; ++q) {
                v4f fv;
                fv.x = h2f((unsigned short)(qs[q].x & 0xffffu));
                fv.y = h2f((unsigned short)(qs[q].y & 0xffffu));
                fv.z = h2f((unsigned short)(qs[q].z & 0xffffu));
                fv.w = h2f((unsigned short)(qs[q].w & 0xffffu));
                *reinterpret_cast<v4f*>(&plane[(q << 10) + 4 * tid]) = fv;
            }
        }
        u_cur = u_nxt;
        __syncthreads();            // new plane ready
    }
}

// ---------------- staged-GEMM stage helpers (global_load_lds width 16) ----------------

static __device__ __forceinline__ void stage128x32(const _Float16* __restrict__ g,
                                                   int ld, int row0, int k0,
                                                   _Float16* lds, int wave, int lane) {
#pragma unroll
    for (int q = 0; q < 2; ++q) {
        int i = wave * 128 + q * 64 + lane;
        const _Float16* src = g + (size_t)(row0 + (i >> 2)) * ld + k0 + (i & 3) * 8;
        int loff = __builtin_amdgcn_readfirstlane((wave * 128 + q * 64) * 16);
        __builtin_amdgcn_global_load_lds(
            (const __attribute__((address_space(1))) void*)src,
            (__attribute__((address_space(3))) void*)((char*)lds + loff),
            16, 0, 0);
    }
}

static __device__ __forceinline__ void stage64x32(const _Float16* __restrict__ g,
                                                  int ld, int row0, int k0,
                                                  _Float16* lds, int wave, int lane) {
    int i = wave * 64 + lane;
    const _Float16* src = g + (size_t)(row0 + (i >> 2)) * ld + k0 + (i & 3) * 8;
    int loff = __builtin_amdgcn_readfirstlane(wave * 64 * 16);
    __builtin_amdgcn_global_load_lds(
        (const __attribute__((address_space(1))) void*)src,
        (__attribute__((address_space(3))) void*)((char*)lds + loff),
        16, 0, 0);
}

// ---------------- GEMM1: Rbh(2048x512,f16) = Hb(2048x4096,f16) @ Bwh^T ----------------
// 64x64 tile -> 256 WGs. 256 thr (4 waves 2x2), BK=32 dbuf.

__global__ __launch_bounds__(256) void k_gemm1(const _Float16* __restrict__ Hb,
                                               const _Float16* __restrict__ Bwh,
                                               unsigned short* __restrict__ Rbh) {
    __shared__ _Float16 As[2][64 * 32];
    __shared__ _Float16 Bs[2][64 * 32];
    int tid = threadIdx.x, lane = tid & 63, wave = tid >> 6;
    int wm = wave >> 1, wn = wave & 1;
    int col0 = blockIdx.x * 64;
    int row0 = blockIdx.y * 64;
    int rA = lane & 15, kA = (lane >> 4) * 8;
    v4f acc[2][2];
#pragma unroll
    for (int s = 0; s < 2; ++s)
#pragma unroll
        for (int f = 0; f < 2; ++f) acc[s][f] = (v4f){0.f, 0.f, 0.f, 0.f};

    stage64x32(Hb,  N_RES, row0, 0, As[0], wave, lane);
    stage64x32(Bwh, N_RES, col0, 0, Bs[0], wave, lane);
    const int NIT = N_RES / 32;   // 128
    for (int it = 0; it < NIT; ++it) {
        int cur = it & 1;
        __syncthreads();
        asm volatile("s_waitcnt vmcnt(0)" ::: "memory");
        __syncthreads();
        if (it + 1 < NIT) {
            stage64x32(Hb,  N_RES, row0, (it + 1) * 32, As[cur ^ 1], wave, lane);
            stage64x32(Bwh, N_RES, col0, (it + 1) * 32, Bs[cur ^ 1], wave, lane);
        }
        v8h af[2], bf[2];
#pragma unroll
        for (int s = 0; s < 2; ++s)
            af[s] = *reinterpret_cast<const v8h*>(&As[cur][(wm * 32 + s * 16 + rA) * 32 + kA]);
#pragma unroll
        for (int f = 0; f < 2; ++f)
            bf[f] = *reinterpret_cast<const v8h*>(&Bs[cur][(wn * 32 + f * 16 + rA) * 32 + kA]);
#pragma unroll
        for (int s = 0; s < 2; ++s)
#pragma unroll
            for (int f = 0; f < 2; ++f)
                acc[s][f] = __builtin_amdgcn_mfma_f32_16x16x32_f16(af[s], bf[f], acc[s][f], 0, 0, 0);
    }
#pragma unroll
    for (int f = 0; f < 2; ++f) {
        int col = col0 + wn * 32 + f * 16 + (lane & 15);
#pragma unroll
        for (int s = 0; s < 2; ++s)
#pragma unroll
            for (int r = 0; r < 4; ++r) {
                int row = row0 + wm * 32 + s * 16 + (lane >> 4) * 4 + r;
                Rbh[(size_t)row * R_OUT + col] = f2h(acc[s][f][r]);
            }
    }
}

// ---------------- GEMM2: out(2048x32000,f32) = Rbh(f16) @ Awh^T + Ab ----------------
// 128x128 tile, BK=64, 32 MFMA per barrier-pair, nontemporal f32 output.

__global__ __launch_bounds__(256) void k_gemm2(const _Float16* __restrict__ Rbh,
                                               const _Float16* __restrict__ Awh,
                                               const float* __restrict__ Ab,
                                               float* __restrict__ out) {
    __shared__ _Float16 As[2][128 * 64];    // 32 KB
    __shared__ _Float16 Bs[2][128 * 64];    // 32 KB
    int tid = threadIdx.x, lane = tid & 63, wave = tid >> 6;
    int wm = wave >> 1, wn = wave & 1;
    int col0 = blockIdx.x * 128;
    int row0 = blockIdx.y * 128;
    int rA = lane & 15, kA = (lane >> 4) * 8;
    v4f acc[4][4];
#pragma unroll
    for (int s = 0; s < 4; ++s)
#pragma unroll
        for (int f = 0; f < 4; ++f) acc[s][f] = (v4f){0.f, 0.f, 0.f, 0.f};

    stage128x32(Rbh, R_OUT, row0, 0,  As[0], wave, lane);
    stage128x32(Rbh, R_OUT, row0, 32, As[0] + 128 * 32, wave, lane);
    stage128x32(Awh, R_OUT, col0, 0,  Bs[0], wave, lane);
    stage128x32(Awh, R_OUT, col0, 32, Bs[0] + 128 * 32, wave, lane);
    const int NIT = R_OUT / 64;   // 8
    for (int it = 0; it < NIT; ++it) {
        int cur = it & 1;
        __syncthreads();
        asm volatile("s_waitcnt vmcnt(0)" ::: "memory");
        __syncthreads();
        if (it + 1 < NIT) {
            int k0 = (it + 1) * 64;
            stage128x32(Rbh, R_OUT, row0, k0,      As[cur ^ 1], wave, lane);
            stage128x32(Rbh, R_OUT, row0, k0 + 32, As[cur ^ 1] + 128 * 32, wave, lane);
            stage128x32(Awh, R_OUT, col0, k0,      Bs[cur ^ 1], wave, lane);
            stage128x32(Awh, R_OUT, col0, k0 + 32, Bs[cur ^ 1] + 128 * 32, wave, lane);
        }
#pragma unroll
        for (int ks = 0; ks < 2; ++ks) {
            const _Float16* ab = &As[cur][ks * 128 * 32];
            const _Float16* bb = &Bs[cur][ks * 128 * 32];
            v8h af[4], bf[4];
#pragma unroll
            for (int s = 0; s < 4; ++s)
                af[s] = *reinterpret_cast<const v8h*>(&ab[(wm * 64 + s * 16 + rA) * 32 + kA]);
#pragma unroll
            for (int f = 0; f < 4; ++f)
                bf[f] = *reinterpret_cast<const v8h*>(&bb[(wn * 64 + f * 16 + rA) * 32 + kA]);
#pragma unroll
            for (int s = 0; s < 4; ++s)
#pragma unroll
                for (int f = 0; f < 4; ++f)
                    acc[s][f] = __builtin_amdgcn_mfma_f32_16x16x32_f16(af[s], bf[f], acc[s][f], 0, 0, 0);
        }
    }
#pragma unroll
    for (int f = 0; f < 4; ++f) {
        float bias = Ab[col0 + wn * 64 + f * 16 + (lane & 15)];
#pragma unroll
        for (int s = 0; s < 4; ++s)
#pragma unroll
            for (int r = 0; r < 4; ++r) acc[s][f][r] += bias;
    }
    // LDS-transposed coalesced epilogue, nontemporal stores
    float* Ct = (float*)As;
#pragma unroll
    for (int s = 0; s < 4; ++s) {
        __syncthreads();
#pragma unroll
        for (int f = 0; f < 4; ++f) {
            int lc = wn * 64 + f * 16 + (lane & 15);
            int lr = wm * 16 + (lane >> 4) * 4;
#pragma unroll
            for (int r = 0; r < 4; ++r)
                Ct[(lr + r) * 128 + lc] = acc[s][f][r];
        }
        __syncthreads();
        int lr2 = tid >> 3;
        int lc2 = (tid & 7) * 16;
        int grow = row0 + (lr2 & 15) + (lr2 >> 4) * 64 + s * 16;
        float* dst = out + (size_t)grow * VOCAB + col0 + lc2;
        const float* srcl = &Ct[lr2 * 128 + lc2];
#pragma unroll
        for (int v = 0; v < 4; ++v)
            __builtin_nontemporal_store(
                *reinterpret_cast<const v4f*>(srcl + v * 4),
                reinterpret_cast<v4f*>(dst + v * 4));
    }
}

// ---------------- host launch ----------------

extern "C" void kernel_launch(void* const* d_in, const int* in_sizes, int n_in,
                              void* d_out, int out_size, void* d_ws, size_t ws_size,
                              hipStream_t stream) {
    const int*   x        = (const int*)d_in[0];
    const float* W_in     = (const float*)d_in[1];
    const int*   rec_rows = (const int*)d_in[2];
    const int*   rec_cols = (const int*)d_in[3];
    const float* rec_vals = (const float*)d_in[4];
    const float* a        = (const float*)d_in[5];
    const float* B_w      = (const float*)d_in[6];
    const float* A_w      = (const float*)d_in[7];
    const float* A_b      = (const float*)d_in[8];
    float* out = (float*)d_out;

    char* w = (char*)d_ws;
    size_t off = 0;
    auto alloc = [&](size_t bytes) { void* p = w + off; off = (off + bytes + 255) & ~(size_t)255; return p; };

    unsigned short* Hb     = (unsigned short*)alloc((size_t)2048 * N_RES * 2);   // 16.8 MB
    unsigned short* Rbh    = (unsigned short*)alloc((size_t)2048 * R_OUT * 2);   // 2.1 MB
    unsigned short* Bwh    = (unsigned short*)alloc((size_t)R_OUT * N_RES * 2);  // 4.2 MB
    unsigned short* Awh    = (unsigned short*)alloc((size_t)VOCAB * R_OUT * 2);  // 32.8 MB
    unsigned*       csr    = (unsigned*)alloc((size_t)NNZ_CAP * 4);              // 655 KB
    int*            rowptr = (int*)alloc(4097 * 4);
    int*            cnt    = (int*)alloc(4096 * 4);
    int*            cursor = (int*)alloc(4096 * 4);
    unsigned*       hx     = (unsigned*)alloc((size_t)HX_WORDS * 4);             // 256 KB
    unsigned*       flags  = (unsigned*)alloc(FLAG_WORDS * 4);                   // 16 KB

    k_init<<<(INIT_WORDS + 255) / 256, 256, 0, stream>>>(csr, cnt, flags, hx);

    k_hist<<<(NNZ + 255) / 256, 256, 0, stream>>>(rec_rows, cnt);
    k_scan<<<1, 1024, 0, stream>>>(cnt, rowptr, cursor);
    k_fill<<<(NNZ + 255) / 256, 256, 0, stream>>>(rec_rows, rec_cols, rec_vals, cursor, csr);

    k_cvt2<<<(NB8 + NA8 + 255) / 256, 256, 0, stream>>>(B_w, Bwh, A_w, Awh);

    k_steps<<<NWG, 256, 0, stream>>>(rowptr, csr, W_in, x, a, Hb, hx, flags);

    k_gemm1<<<dim3(R_OUT / 64, 2048 / 64), 256, 0, stream>>>(
        (const _Float16*)Hb, (const _Float16*)Bwh, Rbh);
    k_gemm2<<<dim3(VOCAB / 128, 2048 / 128), 256, 0, stream>>>(
        (const _Float16*)Rbh, (const _Float16*)Awh, A_b, out);
}

// Round 18
// 1267.133 us; speedup vs baseline: 1.1976x; 1.1976x over previous
//
#include <hip/hip_runtime.h>
#include <hip/hip_bf16.h>
#include <stdint.h>

#define N_RES 4096
#define BATCH 8
#define T_STEPS 256
#define VOCAB 32000
#define R_OUT 512
#define NNZ 131072
#define NNZ_CAP 163840
#define TEAMS 8             // one per batch
#define SLICES 16           // WGs per team
#define ROWS_PS 256         // rows per WG
#define NWG (TEAMS*SLICES)  // 128
#define CSR_CAP 10240       // entries per slice in LDS (mean ~9088, +11 sigma)

typedef _Float16 v8h __attribute__((ext_vector_type(8)));
typedef float v4f __attribute__((ext_vector_type(4)));

static __device__ __forceinline__ unsigned short f2h(float f) {
    _Float16 h = (_Float16)f;
    unsigned short u;
    __builtin_memcpy(&u, &h, 2);
    return u;
}
static __device__ __forceinline__ float h2f(unsigned short u) {
    _Float16 h;
    __builtin_memcpy(&h, &u, 2);
    return (float)h;
}

// ---------------- fused init: zero csr, cnt, flags, hx (one node) ----------------
// hx MUST be zeroed every launch: tags gate reads, and a graph replay would
// otherwise leave last-run tags 254/255 that ALIAS this run's epochs 254/255
// (the no-ack flag can outrun the payload -> stale word validates). With
// hx zeroed, same-parity stale tags are always e-2 != e (or 0) -> safe.

#define FLAG_WORDS (TEAMS * SLICES * 32)        // 4096 u32
#define HX_WORDS   (2 * TEAMS * 4096)           // 65536 u32
#define INIT_WORDS (NNZ_CAP + 4096 + FLAG_WORDS + HX_WORDS)

__global__ __launch_bounds__(256) void k_init(unsigned* __restrict__ csr,
                                              int* __restrict__ cnt,
                                              unsigned* __restrict__ flags,
                                              unsigned* __restrict__ hx) {
    int i = blockIdx.x * 256 + threadIdx.x;
    if (i < NNZ_CAP) csr[i] = 0u;
    else if (i < NNZ_CAP + 4096) cnt[i - NNZ_CAP] = 0;
    else if (i < NNZ_CAP + 4096 + FLAG_WORDS) flags[i - NNZ_CAP - 4096] = 0u;
    else if (i < INIT_WORDS) hx[i - NNZ_CAP - 4096 - FLAG_WORDS] = 0u;
}

// ---------------- CSR build ----------------

__global__ __launch_bounds__(256) void k_hist(const int* __restrict__ rows,
                                              int* __restrict__ cnt) {
    int i = blockIdx.x * 256 + threadIdx.x;
    if (i < NNZ) atomicAdd(&cnt[rows[i]], 1);
}

// padded scan: each row's span rounded up to multiple of 8
__global__ __launch_bounds__(1024) void k_scan(const int* __restrict__ cnt,
                                               int* __restrict__ row_ptr,
                                               int* __restrict__ cursor) {
    __shared__ int sm[1024];
    int t = threadIdx.x;
    int base = t * 4;
    int c0 = (cnt[base] + 7) & ~7;
    int c1 = (cnt[base + 1] + 7) & ~7;
    int c2 = (cnt[base + 2] + 7) & ~7;
    int c3 = (cnt[base + 3] + 7) & ~7;
    int s = c0 + c1 + c2 + c3;
    sm[t] = s;
    __syncthreads();
    for (int off = 1; off < 1024; off <<= 1) {
        int v = (t >= off) ? sm[t - off] : 0;
        __syncthreads();
        sm[t] += v;
        __syncthreads();
    }
    int run = sm[t] - s;
    row_ptr[base] = run;     cursor[base] = run;     run += c0;
    row_ptr[base + 1] = run; cursor[base + 1] = run; run += c1;
    row_ptr[base + 2] = run; cursor[base + 2] = run; run += c2;
    row_ptr[base + 3] = run; cursor[base + 3] = run; run += c3;
    if (t == 1023) row_ptr[4096] = run;
}

// packed CSR entry: plane BYTE offset (col*4) in hi16, f16 value in lo16.
__global__ __launch_bounds__(256) void k_fill(const int* __restrict__ rows,
                                              const int* __restrict__ cols,
                                              const float* __restrict__ vals,
                                              int* __restrict__ cursor,
                                              unsigned* __restrict__ csr) {
    int i = blockIdx.x * 256 + threadIdx.x;
    if (i < NNZ) {
        int r = rows[i];
        unsigned off = (unsigned)(cols[i] << 2);
        int p = atomicAdd(&cursor[r], 1);
        csr[p] = (off << 16) | (unsigned)f2h(vals[i]);
    }
}

// ---------------- fused f32 -> f16 convert: B_w then A_w (one node) ----------------

#define NB8 (R_OUT * N_RES / 8)     // 262144 B_w octets
#define NA8 (VOCAB * R_OUT / 8)     // 2048000 A_w octets

__global__ __launch_bounds__(256) void k_cvt2(const float* __restrict__ Bw,
                                              unsigned short* __restrict__ Bwh,
                                              const float* __restrict__ Aw,
                                              unsigned short* __restrict__ Awh) {
    int i = blockIdx.x * 256 + threadIdx.x;
    const float* src;
    unsigned short* dst;
    int j;
    if (i < NB8) { src = Bw; dst = Bwh; j = i * 8; }
    else if (i < NB8 + NA8) { src = Aw; dst = Awh; j = (i - NB8) * 8; }
    else return;
    float4 a0 = *reinterpret_cast<const float4*>(src + j);
    float4 a1 = *reinterpret_cast<const float4*>(src + j + 4);
    unsigned short o[8] = { f2h(a0.x), f2h(a0.y), f2h(a0.z), f2h(a0.w),
                            f2h(a1.x), f2h(a1.y), f2h(a1.z), f2h(a1.w) };
    *reinterpret_cast<uint4*>(dst + j) = *reinterpret_cast<const uint4*>(o);
}

// ---------------- persistent recurrence: r17 k_steps (proven 980 us) ----------------
// 128 WGs x 256 threads. team = wg&7, slice = wg>>3 (256 rows).
// Publish: ONE relaxed agent store of (epoch<<16)|f16(h) per thread; sync;
// tid0 flag store (no vmcnt ack -- tag catches flag-outruns-payload).
// Gate: tid<16 poll team flags; sync. Pull: 4x dwordx4 sc0 sc1 (16B/lane,
// coalesced), tag-validate, retry stale quads (64 budget, then per-word
// agent fallback -> no hang). Refill: quad q -> rows q*1024+4*tid..+3, ONE
// float4 LDS write (identity layout -> conflict-free).
// Replay safety: hx AND flags zeroed every launch (see k_init comment).

__global__ __launch_bounds__(256) void k_steps(const int* __restrict__ rowptr,
                                               const unsigned* __restrict__ csr,
                                               const float* __restrict__ W_in,
                                               const int* __restrict__ x,
                                               const float* __restrict__ a,
                                               unsigned short* __restrict__ Hb,
                                               unsigned* __restrict__ hx,
                                               unsigned* __restrict__ flags) {
    __shared__ float plane[4096];                       // 16 KB, identity
    __shared__ __align__(16) unsigned lcsr[CSR_CAP];    // 40 KB
    __shared__ int ltok[T_STEPS];                       // 1 KB

    int wg = blockIdx.x;
    int tid = threadIdx.x;
    int team = wg & 7;
    int slice = wg >> 3;
    int r_own = slice * ROWS_PS + tid;

    ltok[tid] = x[team * T_STEPS + tid];

    int j0 = rowptr[slice * ROWS_PS];
    int j1 = rowptr[slice * ROWS_PS + ROWS_PS];
    int cntE = j1 - j0;
    if (cntE > CSR_CAP) cntE = CSR_CAP;
    {
        const uint4* src = reinterpret_cast<const uint4*>(csr + j0);
        int n4 = cntE >> 2;
        for (int k = tid; k < n4; k += 256)
            reinterpret_cast<uint4*>(lcsr)[k] = src[k];
    }
    for (int k = tid; k < 4096; k += 256) plane[k] = 0.f;

    int js = rowptr[r_own] - j0;
    int je = rowptr[r_own + 1] - j0;
    if (js > CSR_CAP) js = CSR_CAP;
    if (je > CSR_CAP) je = CSR_CAP;
    float av = a[r_own];
    float oma = 1.f - av;
    __syncthreads();

    float u_cur = W_in[(size_t)ltok[0] * N_RES + r_own];

    for (int t = 0; t < T_STEPS; ++t) {
        float u_nxt = 0.f;
        if (t + 1 < T_STEPS)
            u_nxt = W_in[(size_t)ltok[t + 1] * N_RES + r_own];   // long shadow

        float acc = 0.f;
        for (int j = js; j < je; j += 8) {
            uint4 e0 = *reinterpret_cast<const uint4*>(lcsr + j);
            uint4 e1 = *reinterpret_cast<const uint4*>(lcsr + j + 4);
            unsigned ee[8] = { e0.x, e0.y, e0.z, e0.w, e1.x, e1.y, e1.z, e1.w };
#pragma unroll
            for (int q = 0; q < 8; ++q) {
                float g = *reinterpret_cast<const float*>(
                    reinterpret_cast<const char*>(plane) + (ee[q] >> 16));
                acc += h2f((unsigned short)(ee[q] & 0xffffu)) * g;
            }
        }
        float hold = plane[r_own];
        float pre = u_cur + acc;
        pre = fminf(fmaxf(pre, -10.f), 10.f);
        float ex = __expf(2.f * pre);
        float th = 1.f - 2.f / (ex + 1.f);
        float hv = oma * hold + av * th;
        unsigned short hv16 = f2h(hv);

        if (t == T_STEPS - 1) {
            Hb[((size_t)(team * T_STEPS + t) << 12) + r_own] = hv16;
            break;
        }

        unsigned e = (unsigned)(t + 1);
        unsigned* xb = hx + (((size_t)(e & 1u) * TEAMS + team) << 12);

        // publish own row: tagged word, fire-and-forget (coalesced per wave)
        __hip_atomic_store(xb + r_own, (e << 16) | (unsigned)hv16,
                           __ATOMIC_RELAXED, __HIP_MEMORY_SCOPE_AGENT);
        __syncthreads();                     // all waves issued their stores
        if (tid == 0)
            __hip_atomic_store(flags + (team * SLICES + slice) * 32, e,
                               __ATOMIC_RELAXED, __HIP_MEMORY_SCOPE_AGENT);

        // off-critical-path work in the flag-propagation shadow
        Hb[((size_t)(team * T_STEPS + t) << 12) + r_own] = hv16;

        // gate: tid<16 poll the 16 team flags
        if (tid < SLICES) {
            const unsigned* fp = flags + (team * SLICES + tid) * 32;
            while (__hip_atomic_load(fp, __ATOMIC_RELAXED,
                                     __HIP_MEMORY_SCOPE_AGENT) < e) {}
        }
        __syncthreads();                     // also: all gathers from plane done

        // bulk pull: 4x dwordx4 (16B/lane, fully coalesced), tag-validated
        uint4 v0, v1, v2, v3;
        const char* p0 = reinterpret_cast<const char*>(xb) + (size_t)tid * 16;
        const char* p1 = p0 + 4096;
        const char* p2 = p0 + 8192;
        const char* p3 = p0 + 12288;
        asm volatile(
            "global_load_dwordx4 %0, %4, off sc0 sc1\n\t"
            "global_load_dwordx4 %1, %5, off sc0 sc1\n\t"
            "global_load_dwordx4 %2, %6, off sc0 sc1\n\t"
            "global_load_dwordx4 %3, %7, off sc0 sc1\n\t"
            "s_waitcnt vmcnt(0)"
            : "=&v"(v0), "=&v"(v1), "=&v"(v2), "=&v"(v3)
            : "v"(p0), "v"(p1), "v"(p2), "v"(p3)
            : "memory");
#define QOK(v) (((v.x >> 16) == e) && ((v.y >> 16) == e) && \
                ((v.z >> 16) == e) && ((v.w >> 16) == e))
        int tries = 0;
        while (!(QOK(v0) && QOK(v1) && QOK(v2) && QOK(v3)) && tries <= 64) {
            ++tries;
            if (!QOK(v0)) asm volatile("global_load_dwordx4 %0, %1, off sc0 sc1\n\ts_waitcnt vmcnt(0)" : "=&v"(v0) : "v"(p0) : "memory");
            if (!QOK(v1)) asm volatile("global_load_dwordx4 %0, %1, off sc0 sc1\n\ts_waitcnt vmcnt(0)" : "=&v"(v1) : "v"(p1) : "memory");
            if (!QOK(v2)) asm volatile("global_load_dwordx4 %0, %1, off sc0 sc1\n\ts_waitcnt vmcnt(0)" : "=&v"(v2) : "v"(p2) : "memory");
            if (!QOK(v3)) asm volatile("global_load_dwordx4 %0, %1, off sc0 sc1\n\ts_waitcnt vmcnt(0)" : "=&v"(v3) : "v"(p3) : "memory");
        }
        if (tries > 64) {
            // guaranteed fallback: per-word agent atomics (always visible)
            unsigned w[16];
#pragma unroll
            for (int k = 0; k < 16; ++k) {
                const unsigned* wp = xb + (k >> 2) * 1024 + tid * 4 + (k & 3);
                unsigned g = __hip_atomic_load(wp, __ATOMIC_RELAXED, __HIP_MEMORY_SCOPE_AGENT);
                while ((g >> 16) != e)
                    g = __hip_atomic_load(wp, __ATOMIC_RELAXED, __HIP_MEMORY_SCOPE_AGENT);
                w[k] = g;
            }
            v0 = (uint4){w[0], w[1], w[2], w[3]};
            v1 = (uint4){w[4], w[5], w[6], w[7]};
            v2 = (uint4){w[8], w[9], w[10], w[11]};
            v3 = (uint4){w[12], w[13], w[14], w[15]};
        }
#undef QOK
        // refill: quad q covers rows q*1024 + 4*tid .. +3 -> ONE float4 write
        {
            uint4 qs[4] = { v0, v1, v2, v3 };
#pragma unroll
            for (int q = 0; q < 4; ++q) {
                v4f fv;
                fv.x = h2f((unsigned short)(qs[q].x & 0xffffu));
                fv.y = h2f((unsigned short)(qs[q].y & 0xffffu));
                fv.z = h2f((unsigned short)(qs[q].z & 0xffffu));
                fv.w = h2f((unsigned short)(qs[q].w & 0xffffu));
                *reinterpret_cast<v4f*>(&plane[(q << 10) + 4 * tid]) = fv;
            }
        }
        u_cur = u_nxt;
        __syncthreads();            // new plane ready
    }
}

// ---------------- staged-GEMM stage helpers (global_load_lds width 16) ----------------

static __device__ __forceinline__ void stage128x32(const _Float16* __restrict__ g,
                                                   int ld, int row0, int k0,
                                                   _Float16* lds, int wave, int lane) {
#pragma unroll
    for (int q = 0; q < 2; ++q) {
        int i = wave * 128 + q * 64 + lane;
        const _Float16* src = g + (size_t)(row0 + (i >> 2)) * ld + k0 + (i & 3) * 8;
        int loff = __builtin_amdgcn_readfirstlane((wave * 128 + q * 64) * 16);
        __builtin_amdgcn_global_load_lds(
            (const __attribute__((address_space(1))) void*)src,
            (__attribute__((address_space(3))) void*)((char*)lds + loff),
            16, 0, 0);
    }
}

static __device__ __forceinline__ void stage64x32(const _Float16* __restrict__ g,
                                                  int ld, int row0, int k0,
                                                  _Float16* lds, int wave, int lane) {
    int i = wave * 64 + lane;
    const _Float16* src = g + (size_t)(row0 + (i >> 2)) * ld + k0 + (i & 3) * 8;
    int loff = __builtin_amdgcn_readfirstlane(wave * 64 * 16);
    __builtin_amdgcn_global_load_lds(
        (const __attribute__((address_space(1))) void*)src,
        (__attribute__((address_space(3))) void*)((char*)lds + loff),
        16, 0, 0);
}

// ---------------- GEMM1: Rbh(2048x512,f16) = Hb(2048x4096,f16) @ Bwh^T ----------------
// 64x64 tile -> 256 WGs. 256 thr (4 waves 2x2), BK=32 dbuf.

__global__ __launch_bounds__(256) void k_gemm1(const _Float16* __restrict__ Hb,
                                               const _Float16* __restrict__ Bwh,
                                               unsigned short* __restrict__ Rbh) {
    __shared__ _Float16 As[2][64 * 32];
    __shared__ _Float16 Bs[2][64 * 32];
    int tid = threadIdx.x, lane = tid & 63, wave = tid >> 6;
    int wm = wave >> 1, wn = wave & 1;
    int col0 = blockIdx.x * 64;
    int row0 = blockIdx.y * 64;
    int rA = lane & 15, kA = (lane >> 4) * 8;
    v4f acc[2][2];
#pragma unroll
    for (int s = 0; s < 2; ++s)
#pragma unroll
        for (int f = 0; f < 2; ++f) acc[s][f] = (v4f){0.f, 0.f, 0.f, 0.f};

    stage64x32(Hb,  N_RES, row0, 0, As[0], wave, lane);
    stage64x32(Bwh, N_RES, col0, 0, Bs[0], wave, lane);
    const int NIT = N_RES / 32;   // 128
    for (int it = 0; it < NIT; ++it) {
        int cur = it & 1;
        __syncthreads();
        asm volatile("s_waitcnt vmcnt(0)" ::: "memory");
        __syncthreads();
        if (it + 1 < NIT) {
            stage64x32(Hb,  N_RES, row0, (it + 1) * 32, As[cur ^ 1], wave, lane);
            stage64x32(Bwh, N_RES, col0, (it + 1) * 32, Bs[cur ^ 1], wave, lane);
        }
        v8h af[2], bf[2];
#pragma unroll
        for (int s = 0; s < 2; ++s)
            af[s] = *reinterpret_cast<const v8h*>(&As[cur][(wm * 32 + s * 16 + rA) * 32 + kA]);
#pragma unroll
        for (int f = 0; f < 2; ++f)
            bf[f] = *reinterpret_cast<const v8h*>(&Bs[cur][(wn * 32 + f * 16 + rA) * 32 + kA]);
#pragma unroll
        for (int s = 0; s < 2; ++s)
#pragma unroll
            for (int f = 0; f < 2; ++f)
                acc[s][f] = __builtin_amdgcn_mfma_f32_16x16x32_f16(af[s], bf[f], acc[s][f], 0, 0, 0);
    }
#pragma unroll
    for (int f = 0; f < 2; ++f) {
        int col = col0 + wn * 32 + f * 16 + (lane & 15);
#pragma unroll
        for (int s = 0; s < 2; ++s)
#pragma unroll
            for (int r = 0; r < 4; ++r) {
                int row = row0 + wm * 32 + s * 16 + (lane >> 4) * 4 + r;
                Rbh[(size_t)row * R_OUT + col] = f2h(acc[s][f][r]);
            }
    }
}

// ---------------- GEMM2: out(2048x32000,f32) = Rbh(f16) @ Awh^T + Ab ----------------
// r14-proven config: 128x128 tile, BK=32 dbuf (32 KB LDS), LDS-transposed
// float4 epilogue with PLAIN stores. grid (250, 16).

__global__ __launch_bounds__(256) void k_gemm2(const _Float16* __restrict__ Rbh,
                                               const _Float16* __restrict__ Awh,
                                               const float* __restrict__ Ab,
                                               float* __restrict__ out) {
    __shared__ _Float16 As[2][128 * 32];
    __shared__ _Float16 Bs[2][128 * 32];
    int tid = threadIdx.x, lane = tid & 63, wave = tid >> 6;
    int wm = wave >> 1, wn = wave & 1;
    int col0 = blockIdx.x * 128;
    int row0 = blockIdx.y * 128;
    int rA = lane & 15, kA = (lane >> 4) * 8;
    v4f acc[4][4];
#pragma unroll
    for (int s = 0; s < 4; ++s)
#pragma unroll
        for (int f = 0; f < 4; ++f) acc[s][f] = (v4f){0.f, 0.f, 0.f, 0.f};

    stage128x32(Rbh, R_OUT, row0, 0, As[0], wave, lane);
    stage128x32(Awh, R_OUT, col0, 0, Bs[0], wave, lane);
    const int NIT = R_OUT / 32;   // 16
    for (int it = 0; it < NIT; ++it) {
        int cur = it & 1;
        __syncthreads();
        asm volatile("s_waitcnt vmcnt(0)" ::: "memory");
        __syncthreads();
        if (it + 1 < NIT) {
            stage128x32(Rbh, R_OUT, row0, (it + 1) * 32, As[cur ^ 1], wave, lane);
            stage128x32(Awh, R_OUT, col0, (it + 1) * 32, Bs[cur ^ 1], wave, lane);
        }
        v8h af[4], bf[4];
#pragma unroll
        for (int s = 0; s < 4; ++s)
            af[s] = *reinterpret_cast<const v8h*>(&As[cur][(wm * 64 + s * 16 + rA) * 32 + kA]);
#pragma unroll
        for (int f = 0; f < 4; ++f)
            bf[f] = *reinterpret_cast<const v8h*>(&Bs[cur][(wn * 64 + f * 16 + rA) * 32 + kA]);
#pragma unroll
        for (int s = 0; s < 4; ++s)
#pragma unroll
            for (int f = 0; f < 4; ++f)
                acc[s][f] = __builtin_amdgcn_mfma_f32_16x16x32_f16(af[s], bf[f], acc[s][f], 0, 0, 0);
    }
#pragma unroll
    for (int f = 0; f < 4; ++f) {
        float bias = Ab[col0 + wn * 64 + f * 16 + (lane & 15)];
#pragma unroll
        for (int s = 0; s < 4; ++s)
#pragma unroll
            for (int r = 0; r < 4; ++r) acc[s][f][r] += bias;
    }
    // LDS-transposed coalesced epilogue (plain float4 stores)
    float* Ct = (float*)As;
#pragma unroll
    for (int s = 0; s < 4; ++s) {
        __syncthreads();
#pragma unroll
        for (int f = 0; f < 4; ++f) {
            int lc = wn * 64 + f * 16 + (lane & 15);
            int lr = wm * 16 + (lane >> 4) * 4;
#pragma unroll
            for (int r = 0; r < 4; ++r)
                Ct[(lr + r) * 128 + lc] = acc[s][f][r];
        }
        __syncthreads();
        int lr2 = tid >> 3;
        int lc2 = (tid & 7) * 16;
        int grow = row0 + (lr2 & 15) + (lr2 >> 4) * 64 + s * 16;
        float* dst = out + (size_t)grow * VOCAB + col0 + lc2;
        const float* srcl = &Ct[lr2 * 128 + lc2];
#pragma unroll
        for (int v = 0; v < 4; ++v)
            *reinterpret_cast<float4*>(dst + v * 4) =
                *reinterpret_cast<const float4*>(srcl + v * 4);
    }
}

// ---------------- host launch ----------------

extern "C" void kernel_launch(void* const* d_in, const int* in_sizes, int n_in,
                              void* d_out, int out_size, void* d_ws, size_t ws_size,
                              hipStream_t stream) {
    const int*   x        = (const int*)d_in[0];
    const float* W_in     = (const float*)d_in[1];
    const int*   rec_rows = (const int*)d_in[2];
    const int*   rec_cols = (const int*)d_in[3];
    const float* rec_vals = (const float*)d_in[4];
    const float* a        = (const float*)d_in[5];
    const float* B_w      = (const float*)d_in[6];
    const float* A_w      = (const float*)d_in[7];
    const float* A_b      = (const float*)d_in[8];
    float* out = (float*)d_out;

    char* w = (char*)d_ws;
    size_t off = 0;
    auto alloc = [&](size_t bytes) { void* p = w + off; off = (off + bytes + 255) & ~(size_t)255; return p; };

    unsigned short* Hb     = (unsigned short*)alloc((size_t)2048 * N_RES * 2);   // 16.8 MB
    unsigned short* Rbh    = (unsigned short*)alloc((size_t)2048 * R_OUT * 2);   // 2.1 MB
    unsigned short* Bwh    = (unsigned short*)alloc((size_t)R_OUT * N_RES * 2);  // 4.2 MB
    unsigned short* Awh    = (unsigned short*)alloc((size_t)VOCAB * R_OUT * 2);  // 32.8 MB
    unsigned*       csr    = (unsigned*)alloc((size_t)NNZ_CAP * 4);              // 655 KB
    int*            rowptr = (int*)alloc(4097 * 4);
    int*            cnt    = (int*)alloc(4096 * 4);
    int*            cursor = (int*)alloc(4096 * 4);
    unsigned*       hx     = (unsigned*)alloc((size_t)HX_WORDS * 4);             // 256 KB
    unsigned*       flags  = (unsigned*)alloc(FLAG_WORDS * 4);                   // 16 KB

    k_init<<<(INIT_WORDS + 255) / 256, 256, 0, stream>>>(csr, cnt, flags, hx);

    k_hist<<<(NNZ + 255) / 256, 256, 0, stream>>>(rec_rows, cnt);
    k_scan<<<1, 1024, 0, stream>>>(cnt, rowptr, cursor);
    k_fill<<<(NNZ + 255) / 256, 256, 0, stream>>>(rec_rows, rec_cols, rec_vals, cursor, csr);

    k_cvt2<<<(NB8 + NA8 + 255) / 256, 256, 0, stream>>>(B_w, Bwh, A_w, Awh);

    k_steps<<<NWG, 256, 0, stream>>>(rowptr, csr, W_in, x, a, Hb, hx, flags);

    k_gemm1<<<dim3(R_OUT / 64, 2048 / 64), 256, 0, stream>>>(
        (const _Float16*)Hb, (const _Float16*)Bwh, Rbh);
    k_gemm2<<<dim3(VOCAB / 128, 2048 / 128), 256, 0, stream>>>(
        (const _Float16*)Rbh, (const _Float16*)Awh, A_b, out);
}

// Round 19
// 1239.140 us; speedup vs baseline: 1.2246x; 1.0226x over previous
//
#include <hip/hip_runtime.h>
#include <hip/hip_bf16.h>
#include <stdint.h>

#define N_RES 4096
#define BATCH 8
#define T_STEPS 256
#define VOCAB 32000
#define R_OUT 512
#define NNZ 131072
#define NNZ_CAP 163840
#define TEAMS 8             // one per batch
#define SLICES 16           // WGs per team
#define ROWS_PS 256         // rows per WG
#define NWG (TEAMS*SLICES)  // 128 protocol WGs
#define CVT_WGS 96          // extra WGs folded into k_steps for weight cvt
#define CSR_CAP 10240       // entries per slice in LDS (mean ~9088, +11 sigma)

typedef _Float16 v8h __attribute__((ext_vector_type(8)));
typedef float v4f __attribute__((ext_vector_type(4)));

static __device__ __forceinline__ unsigned short f2h(float f) {
    _Float16 h = (_Float16)f;
    unsigned short u;
    __builtin_memcpy(&u, &h, 2);
    return u;
}
static __device__ __forceinline__ float h2f(unsigned short u) {
    _Float16 h;
    __builtin_memcpy(&h, &u, 2);
    return (float)h;
}

// ---------------- fused init: zero csr, cnt, flags, hx (one node) ----------------
// hx MUST be zeroed every launch: tags gate reads, and a graph replay would
// otherwise leave last-run tags 254/255 that ALIAS this run's epochs 254/255
// (the no-ack flag can outrun the payload -> stale word validates). With
// hx zeroed, same-parity stale tags are always e-2 != e (or 0) -> safe.

#define FLAG_WORDS (TEAMS * SLICES * 32)        // 4096 u32
#define HX_WORDS   (2 * TEAMS * 4096)           // 65536 u32
#define INIT_WORDS (NNZ_CAP + 4096 + FLAG_WORDS + HX_WORDS)

__global__ __launch_bounds__(256) void k_init(unsigned* __restrict__ csr,
                                              int* __restrict__ cnt,
                                              unsigned* __restrict__ flags,
                                              unsigned* __restrict__ hx) {
    int i = blockIdx.x * 256 + threadIdx.x;
    if (i < NNZ_CAP) csr[i] = 0u;
    else if (i < NNZ_CAP + 4096) cnt[i - NNZ_CAP] = 0;
    else if (i < NNZ_CAP + 4096 + FLAG_WORDS) flags[i - NNZ_CAP - 4096] = 0u;
    else if (i < INIT_WORDS) hx[i - NNZ_CAP - 4096 - FLAG_WORDS] = 0u;
}

// ---------------- CSR build ----------------

__global__ __launch_bounds__(256) void k_hist(const int* __restrict__ rows,
                                              int* __restrict__ cnt) {
    int i = blockIdx.x * 256 + threadIdx.x;
    if (i < NNZ) atomicAdd(&cnt[rows[i]], 1);
}

// padded scan: each row's span rounded up to multiple of 8
__global__ __launch_bounds__(1024) void k_scan(const int* __restrict__ cnt,
                                               int* __restrict__ row_ptr,
                                               int* __restrict__ cursor) {
    __shared__ int sm[1024];
    int t = threadIdx.x;
    int base = t * 4;
    int c0 = (cnt[base] + 7) & ~7;
    int c1 = (cnt[base + 1] + 7) & ~7;
    int c2 = (cnt[base + 2] + 7) & ~7;
    int c3 = (cnt[base + 3] + 7) & ~7;
    int s = c0 + c1 + c2 + c3;
    sm[t] = s;
    __syncthreads();
    for (int off = 1; off < 1024; off <<= 1) {
        int v = (t >= off) ? sm[t - off] : 0;
        __syncthreads();
        sm[t] += v;
        __syncthreads();
    }
    int run = sm[t] - s;
    row_ptr[base] = run;     cursor[base] = run;     run += c0;
    row_ptr[base + 1] = run; cursor[base + 1] = run; run += c1;
    row_ptr[base + 2] = run; cursor[base + 2] = run; run += c2;
    row_ptr[base + 3] = run; cursor[base + 3] = run; run += c3;
    if (t == 1023) row_ptr[4096] = run;
}

// packed CSR entry: plane BYTE offset (col*4) in hi16, f16 value in lo16.
__global__ __launch_bounds__(256) void k_fill(const int* __restrict__ rows,
                                              const int* __restrict__ cols,
                                              const float* __restrict__ vals,
                                              int* __restrict__ cursor,
                                              unsigned* __restrict__ csr) {
    int i = blockIdx.x * 256 + threadIdx.x;
    if (i < NNZ) {
        int r = rows[i];
        unsigned off = (unsigned)(cols[i] << 2);
        int p = atomicAdd(&cursor[r], 1);
        csr[p] = (off << 16) | (unsigned)f2h(vals[i]);
    }
}

#define NB8 (R_OUT * N_RES / 8)     // 262144 B_w octets
#define NA8 (VOCAB * R_OUT / 8)     // 2048000 A_w octets

// ---------------- persistent recurrence + folded weight conversion ----------------
// Grid = NWG + CVT_WGS. WGs >= NWG grid-stride the B_w/A_w f32->f16
// conversion (independent of the recurrence; no flags/hx access) and exit —
// their ~110 MB of traffic hides under the protocol WGs' latency stalls.
// All 224 WGs co-resident (57KB LDS -> 2 WGs/CU, 256 CUs), so the protocol
// WGs' co-residency is unaffected; no new deadlock modes.
//
// Protocol (r17/r18-proven, 977 us): 128 WGs x 256 thr, team=wg&7,
// slice=wg>>3. Publish: ONE relaxed agent store of (epoch<<16)|f16(h);
// sync; tid0 flag store (no vmcnt ack -- tag catches flag-outruns-payload).
// Gate: tid<16 poll team flags; sync. Pull: 4x dwordx4 sc0 sc1 coalesced,
// tag-validate, retry stale quads (64 budget, then per-word agent fallback
// -> no hang). Refill: one float4 per quad, identity plane, conflict-free.
// Replay safety: hx AND flags zeroed every launch (see k_init comment).

__global__ __launch_bounds__(256) void k_steps(const int* __restrict__ rowptr,
                                               const unsigned* __restrict__ csr,
                                               const float* __restrict__ W_in,
                                               const int* __restrict__ x,
                                               const float* __restrict__ a,
                                               unsigned short* __restrict__ Hb,
                                               unsigned* __restrict__ hx,
                                               unsigned* __restrict__ flags,
                                               const float* __restrict__ Bw,
                                               unsigned short* __restrict__ Bwh,
                                               const float* __restrict__ Aw,
                                               unsigned short* __restrict__ Awh) {
    __shared__ float plane[4096];                       // 16 KB, identity
    __shared__ __align__(16) unsigned lcsr[CSR_CAP];    // 40 KB
    __shared__ int ltok[T_STEPS];                       // 1 KB

    int wg = blockIdx.x;
    int tid = threadIdx.x;

    if (wg >= NWG) {
        // -------- folded cvt: grid-stride over B_w then A_w octets --------
        for (int i = (wg - NWG) * 256 + tid; i < NB8 + NA8; i += CVT_WGS * 256) {
            const float* src;
            unsigned short* dst;
            int j;
            if (i < NB8) { src = Bw; dst = Bwh; j = i * 8; }
            else { src = Aw; dst = Awh; j = (i - NB8) * 8; }
            float4 a0 = *reinterpret_cast<const float4*>(src + j);
            float4 a1 = *reinterpret_cast<const float4*>(src + j + 4);
            unsigned short o[8] = { f2h(a0.x), f2h(a0.y), f2h(a0.z), f2h(a0.w),
                                    f2h(a1.x), f2h(a1.y), f2h(a1.z), f2h(a1.w) };
            *reinterpret_cast<uint4*>(dst + j) = *reinterpret_cast<const uint4*>(o);
        }
        return;
    }

    int team = wg & 7;
    int slice = wg >> 3;
    int r_own = slice * ROWS_PS + tid;

    ltok[tid] = x[team * T_STEPS + tid];

    int j0 = rowptr[slice * ROWS_PS];
    int j1 = rowptr[slice * ROWS_PS + ROWS_PS];
    int cntE = j1 - j0;
    if (cntE > CSR_CAP) cntE = CSR_CAP;
    {
        const uint4* src = reinterpret_cast<const uint4*>(csr + j0);
        int n4 = cntE >> 2;
        for (int k = tid; k < n4; k += 256)
            reinterpret_cast<uint4*>(lcsr)[k] = src[k];
    }
    for (int k = tid; k < 4096; k += 256) plane[k] = 0.f;

    int js = rowptr[r_own] - j0;
    int je = rowptr[r_own + 1] - j0;
    if (js > CSR_CAP) js = CSR_CAP;
    if (je > CSR_CAP) je = CSR_CAP;
    float av = a[r_own];
    float oma = 1.f - av;
    __syncthreads();

    float u_cur = W_in[(size_t)ltok[0] * N_RES + r_own];

    for (int t = 0; t < T_STEPS; ++t) {
        float u_nxt = 0.f;
        if (t + 1 < T_STEPS)
            u_nxt = W_in[(size_t)ltok[t + 1] * N_RES + r_own];   // long shadow

        float acc = 0.f;
        for (int j = js; j < je; j += 8) {
            uint4 e0 = *reinterpret_cast<const uint4*>(lcsr + j);
            uint4 e1 = *reinterpret_cast<const uint4*>(lcsr + j + 4);
            unsigned ee[8] = { e0.x, e0.y, e0.z, e0.w, e1.x, e1.y, e1.z, e1.w };
#pragma unroll
            for (int q = 0; q < 8; ++q) {
                float g = *reinterpret_cast<const float*>(
                    reinterpret_cast<const char*>(plane) + (ee[q] >> 16));
                acc += h2f((unsigned short)(ee[q] & 0xffffu)) * g;
            }
        }
        float hold = plane[r_own];
        float pre = u_cur + acc;
        pre = fminf(fmaxf(pre, -10.f), 10.f);
        float ex = __expf(2.f * pre);
        float th = 1.f - 2.f / (ex + 1.f);
        float hv = oma * hold + av * th;
        unsigned short hv16 = f2h(hv);

        if (t == T_STEPS - 1) {
            Hb[((size_t)(team * T_STEPS + t) << 12) + r_own] = hv16;
            break;
        }

        unsigned e = (unsigned)(t + 1);
        unsigned* xb = hx + (((size_t)(e & 1u) * TEAMS + team) << 12);

        // publish own row: tagged word, fire-and-forget (coalesced per wave)
        __hip_atomic_store(xb + r_own, (e << 16) | (unsigned)hv16,
                           __ATOMIC_RELAXED, __HIP_MEMORY_SCOPE_AGENT);
        __syncthreads();                     // all waves issued their stores
        if (tid == 0)
            __hip_atomic_store(flags + (team * SLICES + slice) * 32, e,
                               __ATOMIC_RELAXED, __HIP_MEMORY_SCOPE_AGENT);

        // off-critical-path work in the flag-propagation shadow
        Hb[((size_t)(team * T_STEPS + t) << 12) + r_own] = hv16;

        // gate: tid<16 poll the 16 team flags
        if (tid < SLICES) {
            const unsigned* fp = flags + (team * SLICES + tid) * 32;
            while (__hip_atomic_load(fp, __ATOMIC_RELAXED,
                                     __HIP_MEMORY_SCOPE_AGENT) < e) {}
        }
        __syncthreads();                     // also: all gathers from plane done

        // bulk pull: 4x dwordx4 (16B/lane, fully coalesced), tag-validated
        uint4 v0, v1, v2, v3;
        const char* p0 = reinterpret_cast<const char*>(xb) + (size_t)tid * 16;
        const char* p1 = p0 + 4096;
        const char* p2 = p0 + 8192;
        const char* p3 = p0 + 12288;
        asm volatile(
            "global_load_dwordx4 %0, %4, off sc0 sc1\n\t"
            "global_load_dwordx4 %1, %5, off sc0 sc1\n\t"
            "global_load_dwordx4 %2, %6, off sc0 sc1\n\t"
            "global_load_dwordx4 %3, %7, off sc0 sc1\n\t"
            "s_waitcnt vmcnt(0)"
            : "=&v"(v0), "=&v"(v1), "=&v"(v2), "=&v"(v3)
            : "v"(p0), "v"(p1), "v"(p2), "v"(p3)
            : "memory");
#define QOK(v) (((v.x >> 16) == e) && ((v.y >> 16) == e) && \
                ((v.z >> 16) == e) && ((v.w >> 16) == e))
        int tries = 0;
        while (!(QOK(v0) && QOK(v1) && QOK(v2) && QOK(v3)) && tries <= 64) {
            ++tries;
            if (!QOK(v0)) asm volatile("global_load_dwordx4 %0, %1, off sc0 sc1\n\ts_waitcnt vmcnt(0)" : "=&v"(v0) : "v"(p0) : "memory");
            if (!QOK(v1)) asm volatile("global_load_dwordx4 %0, %1, off sc0 sc1\n\ts_waitcnt vmcnt(0)" : "=&v"(v1) : "v"(p1) : "memory");
            if (!QOK(v2)) asm volatile("global_load_dwordx4 %0, %1, off sc0 sc1\n\ts_waitcnt vmcnt(0)" : "=&v"(v2) : "v"(p2) : "memory");
            if (!QOK(v3)) asm volatile("global_load_dwordx4 %0, %1, off sc0 sc1\n\ts_waitcnt vmcnt(0)" : "=&v"(v3) : "v"(p3) : "memory");
        }
        if (tries > 64) {
            // guaranteed fallback: per-word agent atomics (always visible)
            unsigned w[16];
#pragma unroll
            for (int k = 0; k < 16; ++k) {
                const unsigned* wp = xb + (k >> 2) * 1024 + tid * 4 + (k & 3);
                unsigned g = __hip_atomic_load(wp, __ATOMIC_RELAXED, __HIP_MEMORY_SCOPE_AGENT);
                while ((g >> 16) != e)
                    g = __hip_atomic_load(wp, __ATOMIC_RELAXED, __HIP_MEMORY_SCOPE_AGENT);
                w[k] = g;
            }
            v0 = (uint4){w[0], w[1], w[2], w[3]};
            v1 = (uint4){w[4], w[5], w[6], w[7]};
            v2 = (uint4){w[8], w[9], w[10], w[11]};
            v3 = (uint4){w[12], w[13], w[14], w[15]};
        }
#undef QOK
        // refill: quad q covers rows q*1024 + 4*tid .. +3 -> ONE float4 write
        {
            uint4 qs[4] = { v0, v1, v2, v3 };
#pragma unroll
            for (int q = 0; q < 4; ++q) {
                v4f fv;
                fv.x = h2f((unsigned short)(qs[q].x & 0xffffu));
                fv.y = h2f((unsigned short)(qs[q].y & 0xffffu));
                fv.z = h2f((unsigned short)(qs[q].z & 0xffffu));
                fv.w = h2f((unsigned short)(qs[q].w & 0xffffu));
                *reinterpret_cast<v4f*>(&plane[(q << 10) + 4 * tid]) = fv;
            }
        }
        u_cur = u_nxt;
        __syncthreads();            // new plane ready
    }
}

// ---------------- staged-GEMM stage helpers (global_load_lds width 16) ----------------

static __device__ __forceinline__ void stage128x32(const _Float16* __restrict__ g,
                                                   int ld, int row0, int k0,
                                                   _Float16* lds, int wave, int lane) {
#pragma unroll
    for (int q = 0; q < 2; ++q) {
        int i = wave * 128 + q * 64 + lane;
        const _Float16* src = g + (size_t)(row0 + (i >> 2)) * ld + k0 + (i & 3) * 8;
        int loff = __builtin_amdgcn_readfirstlane((wave * 128 + q * 64) * 16);
        __builtin_amdgcn_global_load_lds(
            (const __attribute__((address_space(1))) void*)src,
            (__attribute__((address_space(3))) void*)((char*)lds + loff),
            16, 0, 0);
    }
}

static __device__ __forceinline__ void stage64x32(const _Float16* __restrict__ g,
                                                  int ld, int row0, int k0,
                                                  _Float16* lds, int wave, int lane) {
    int i = wave * 64 + lane;
    const _Float16* src = g + (size_t)(row0 + (i >> 2)) * ld + k0 + (i & 3) * 8;
    int loff = __builtin_amdgcn_readfirstlane(wave * 64 * 16);
    __builtin_amdgcn_global_load_lds(
        (const __attribute__((address_space(1))) void*)src,
        (__attribute__((address_space(3))) void*)((char*)lds + loff),
        16, 0, 0);
}

// ---------------- GEMM1: Rbh(2048x512,f16) = Hb(2048x4096,f16) @ Bwh^T ----------------
// 64x64 tile -> 256 WGs. 256 thr (4 waves 2x2), BK=32 dbuf.

__global__ __launch_bounds__(256) void k_gemm1(const _Float16* __restrict__ Hb,
                                               const _Float16* __restrict__ Bwh,
                                               unsigned short* __restrict__ Rbh) {
    __shared__ _Float16 As[2][64 * 32];
    __shared__ _Float16 Bs[2][64 * 32];
    int tid = threadIdx.x, lane = tid & 63, wave = tid >> 6;
    int wm = wave >> 1, wn = wave & 1;
    int col0 = blockIdx.x * 64;
    int row0 = blockIdx.y * 64;
    int rA = lane & 15, kA = (lane >> 4) * 8;
    v4f acc[2][2];
#pragma unroll
    for (int s = 0; s < 2; ++s)
#pragma unroll
        for (int f = 0; f < 2; ++f) acc[s][f] = (v4f){0.f, 0.f, 0.f, 0.f};

    stage64x32(Hb,  N_RES, row0, 0, As[0], wave, lane);
    stage64x32(Bwh, N_RES, col0, 0, Bs[0], wave, lane);
    const int NIT = N_RES / 32;   // 128
    for (int it = 0; it < NIT; ++it) {
        int cur = it & 1;
        __syncthreads();
        asm volatile("s_waitcnt vmcnt(0)" ::: "memory");
        __syncthreads();
        if (it + 1 < NIT) {
            stage64x32(Hb,  N_RES, row0, (it + 1) * 32, As[cur ^ 1], wave, lane);
            stage64x32(Bwh, N_RES, col0, (it + 1) * 32, Bs[cur ^ 1], wave, lane);
        }
        v8h af[2], bf[2];
#pragma unroll
        for (int s = 0; s < 2; ++s)
            af[s] = *reinterpret_cast<const v8h*>(&As[cur][(wm * 32 + s * 16 + rA) * 32 + kA]);
#pragma unroll
        for (int f = 0; f < 2; ++f)
            bf[f] = *reinterpret_cast<const v8h*>(&Bs[cur][(wn * 32 + f * 16 + rA) * 32 + kA]);
#pragma unroll
        for (int s = 0; s < 2; ++s)
#pragma unroll
            for (int f = 0; f < 2; ++f)
                acc[s][f] = __builtin_amdgcn_mfma_f32_16x16x32_f16(af[s], bf[f], acc[s][f], 0, 0, 0);
    }
#pragma unroll
    for (int f = 0; f < 2; ++f) {
        int col = col0 + wn * 32 + f * 16 + (lane & 15);
#pragma unroll
        for (int s = 0; s < 2; ++s)
#pragma unroll
            for (int r = 0; r < 4; ++r) {
                int row = row0 + wm * 32 + s * 16 + (lane >> 4) * 4 + r;
                Rbh[(size_t)row * R_OUT + col] = f2h(acc[s][f][r]);
            }
    }
}

// ---------------- GEMM2: out(2048x32000,f32) = Rbh(f16) @ Awh^T + Ab ----------------
// r14-proven config: 128x128 tile, BK=32 dbuf (32 KB LDS), LDS-transposed
// float4 epilogue with PLAIN stores. grid (250, 16).

__global__ __launch_bounds__(256) void k_gemm2(const _Float16* __restrict__ Rbh,
                                               const _Float16* __restrict__ Awh,
                                               const float* __restrict__ Ab,
                                               float* __restrict__ out) {
    __shared__ _Float16 As[2][128 * 32];
    __shared__ _Float16 Bs[2][128 * 32];
    int tid = threadIdx.x, lane = tid & 63, wave = tid >> 6;
    int wm = wave >> 1, wn = wave & 1;
    int col0 = blockIdx.x * 128;
    int row0 = blockIdx.y * 128;
    int rA = lane & 15, kA = (lane >> 4) * 8;
    v4f acc[4][4];
#pragma unroll
    for (int s = 0; s < 4; ++s)
#pragma unroll
        for (int f = 0; f < 4; ++f) acc[s][f] = (v4f){0.f, 0.f, 0.f, 0.f};

    stage128x32(Rbh, R_OUT, row0, 0, As[0], wave, lane);
    stage128x32(Awh, R_OUT, col0, 0, Bs[0], wave, lane);
    const int NIT = R_OUT / 32;   // 16
    for (int it = 0; it < NIT; ++it) {
        int cur = it & 1;
        __syncthreads();
        asm volatile("s_waitcnt vmcnt(0)" ::: "memory");
        __syncthreads();
        if (it + 1 < NIT) {
            stage128x32(Rbh, R_OUT, row0, (it + 1) * 32, As[cur ^ 1], wave, lane);
            stage128x32(Awh, R_OUT, col0, (it + 1) * 32, Bs[cur ^ 1], wave, lane);
        }
        v8h af[4], bf[4];
#pragma unroll
        for (int s = 0; s < 4; ++s)
            af[s] = *reinterpret_cast<const v8h*>(&As[cur][(wm * 64 + s * 16 + rA) * 32 + kA]);
#pragma unroll
        for (int f = 0; f < 4; ++f)
            bf[f] = *reinterpret_cast<const v8h*>(&Bs[cur][(wn * 64 + f * 16 + rA) * 32 + kA]);
#pragma unroll
        for (int s = 0; s < 4; ++s)
#pragma unroll
            for (int f = 0; f < 4; ++f)
                acc[s][f] = __builtin_amdgcn_mfma_f32_16x16x32_f16(af[s], bf[f], acc[s][f], 0, 0, 0);
    }
#pragma unroll
    for (int f = 0; f < 4; ++f) {
        float bias = Ab[col0 + wn * 64 + f * 16 + (lane & 15)];
#pragma unroll
        for (int s = 0; s < 4; ++s)
#pragma unroll
            for (int r = 0; r < 4; ++r) acc[s][f][r] += bias;
    }
    // LDS-transposed coalesced epilogue (plain float4 stores)
    float* Ct = (float*)As;
#pragma unroll
    for (int s = 0; s < 4; ++s) {
        __syncthreads();
#pragma unroll
        for (int f = 0; f < 4; ++f) {
            int lc = wn * 64 + f * 16 + (lane & 15);
            int lr = wm * 16 + (lane >> 4) * 4;
#pragma unroll
            for (int r = 0; r < 4; ++r)
                Ct[(lr + r) * 128 + lc] = acc[s][f][r];
        }
        __syncthreads();
        int lr2 = tid >> 3;
        int lc2 = (tid & 7) * 16;
        int grow = row0 + (lr2 & 15) + (lr2 >> 4) * 64 + s * 16;
        float* dst = out + (size_t)grow * VOCAB + col0 + lc2;
        const float* srcl = &Ct[lr2 * 128 + lc2];
#pragma unroll
        for (int v = 0; v < 4; ++v)
            *reinterpret_cast<float4*>(dst + v * 4) =
                *reinterpret_cast<const float4*>(srcl + v * 4);
    }
}

// ---------------- host launch ----------------

extern "C" void kernel_launch(void* const* d_in, const int* in_sizes, int n_in,
                              void* d_out, int out_size, void* d_ws, size_t ws_size,
                              hipStream_t stream) {
    const int*   x        = (const int*)d_in[0];
    const float* W_in     = (const float*)d_in[1];
    const int*   rec_rows = (const int*)d_in[2];
    const int*   rec_cols = (const int*)d_in[3];
    const float* rec_vals = (const float*)d_in[4];
    const float* a        = (const float*)d_in[5];
    const float* B_w      = (const float*)d_in[6];
    const float* A_w      = (const float*)d_in[7];
    const float* A_b      = (const float*)d_in[8];
    float* out = (float*)d_out;

    char* w = (char*)d_ws;
    size_t off = 0;
    auto alloc = [&](size_t bytes) { void* p = w + off; off = (off + bytes + 255) & ~(size_t)255; return p; };

    unsigned short* Hb     = (unsigned short*)alloc((size_t)2048 * N_RES * 2);   // 16.8 MB
    unsigned short* Rbh    = (unsigned short*)alloc((size_t)2048 * R_OUT * 2);   // 2.1 MB
    unsigned short* Bwh    = (unsigned short*)alloc((size_t)R_OUT * N_RES * 2);  // 4.2 MB
    unsigned short* Awh    = (unsigned short*)alloc((size_t)VOCAB * R_OUT * 2);  // 32.8 MB
    unsigned*       csr    = (unsigned*)alloc((size_t)NNZ_CAP * 4);              // 655 KB
    int*            rowptr = (int*)alloc(4097 * 4);
    int*            cnt    = (int*)alloc(4096 * 4);
    int*            cursor = (int*)alloc(4096 * 4);
    unsigned*       hx     = (unsigned*)alloc((size_t)HX_WORDS * 4);             // 256 KB
    unsigned*       flags  = (unsigned*)alloc(FLAG_WORDS * 4);                   // 16 KB

    k_init<<<(INIT_WORDS + 255) / 256, 256, 0, stream>>>(csr, cnt, flags, hx);

    k_hist<<<(NNZ + 255) / 256, 256, 0, stream>>>(rec_rows, cnt);
    k_scan<<<1, 1024, 0, stream>>>(cnt, rowptr, cursor);
    k_fill<<<(NNZ + 255) / 256, 256, 0, stream>>>(rec_rows, rec_cols, rec_vals, cursor, csr);

    k_steps<<<NWG + CVT_WGS, 256, 0, stream>>>(rowptr, csr, W_in, x, a, Hb, hx, flags,
                                               B_w, Bwh, A_w, Awh);

    k_gemm1<<<dim3(R_OUT / 64, 2048 / 64), 256, 0, stream>>>(
        (const _Float16*)Hb, (const _Float16*)Bwh, Rbh);
    k_gemm2<<<dim3(VOCAB / 128, 2048 / 128), 256, 0, stream>>>(
        (const _Float16*)Rbh, (const _Float16*)Awh, A_b, out);
}